// Round 18
// baseline (91.203 us; speedup 1.0000x reference)
//
#include <hip/hip_runtime.h>
#include <hip/hip_bf16.h>

typedef float f32x4 __attribute__((ext_vector_type(4)));

#define NROWS 8192
#define HALF_N 4096
#define DIM 128
#define C1 14.42695040888963f    /* (1/T) * log2(e) */
#define LN2 0.6931471805599453f
#define NSTRIP 2112              /* triangle strips: sum_q 4*(32-q) */
#define GBLK (NSTRIP / 4)        /* 528 blocks, 4 strips (waves) each */

/* fp8 packed MFMA-operand layout (R14-verified, absmax 0): rows in groups of
   16; group g (2048 B) holds rows [g*16,+16). Within a group: 4 ks-regions of
   512 B; byte lane*8 of region ks = 8-value k-chunk of row (g*16+(lane&15)).
   One wave fragment load = one fully-coalesced 512 B global_load_dwordx2.
   A and B share the mapping so intra-dot k-permutations cancel. */

// ---- kernel 1: normalize (i,j) pairs -> packA(=rn*C1 fp8), packB(=rn fp8) --
__global__ __launch_bounds__(256) void k_normalize(
    const float* __restrict__ zi, const float* __restrict__ zj,
    char* __restrict__ packA, char* __restrict__ packB,
    float* __restrict__ rowsum, float* __restrict__ pbuf,
    unsigned int* __restrict__ done)
{
    const int wave = threadIdx.x >> 6;
    const int lane = threadIdx.x & 63;
    const int ks_  = lane >> 4;
    const int qr_  = (lane >> 2) & 3;
    const int rem_ = (lane & 3) * 2;          // byte pos of this lane's 2 vals
    #pragma unroll
    for (int t = 0; t < 2; ++t) {
        const int idx = blockIdx.x * 8 + wave * 2 + t;   // i-row; partner idx+N
        float2 vi = *(const float2*)(zi + (size_t)idx * DIM + lane * 2);
        float2 vj = *(const float2*)(zj + (size_t)idx * DIM + lane * 2);
        float ssi = vi.x * vi.x + vi.y * vi.y;
        float ssj = vj.x * vj.x + vj.y * vj.y;
        float cr  = vi.x * vj.x + vi.y * vj.y;
        #pragma unroll
        for (int m = 32; m >= 1; m >>= 1) {
            ssi += __shfl_xor(ssi, m, 64);
            ssj += __shfl_xor(ssj, m, 64);
            cr  += __shfl_xor(cr,  m, 64);
        }
        const float sci = 1.0f / fmaxf(sqrtf(ssi), 1e-8f);
        const float scj = 1.0f / fmaxf(sqrtf(ssj), 1e-8f);
        #pragma unroll
        for (int h = 0; h < 2; ++h) {                 // h=0: i-row, h=1: j-row
            const int   row = idx + h * HALF_N;
            const float sx  = h ? vj.x * scj : vi.x * sci;
            const float sy  = h ? vj.y * scj : vi.y * sci;
            const size_t off = (size_t)(row >> 4) * 2048 + ks_ * 512
                             + (qr_ * 16 + (row & 15)) * 8 + rem_;
            unsigned ua = __builtin_amdgcn_cvt_pk_fp8_f32(sx * C1, sy * C1, 0, false);
            unsigned ub = __builtin_amdgcn_cvt_pk_fp8_f32(sx,      sy,      0, false);
            *(unsigned short*)(packA + off) = (unsigned short)ua;
            *(unsigned short*)(packB + off) = (unsigned short)ub;
        }
        if (lane == 0) {
            const float p = cr * sci * scj;   // exact f32 positive-pair cosine
            pbuf[idx] = p;
            pbuf[idx + HALF_N] = p;
        }
    }
    if (threadIdx.x < 16) rowsum[blockIdx.x * 16 + threadIdx.x] = 0.0f;
    if (blockIdx.x == 0 && threadIdx.x == 0) *done = 0u;
}

// ---- kernel 2: symmetry-halved fp8 sim GEMM, STEP-ROTATED B order ----------
// R17 body with one delta: off-diagonal strips traverse their 16 B-chunks in
// an order rotated by (rg&15). Rationale: 66 strips share each cv and (R17)
// all hit the SAME 2 KB chunk at the same phase -> same-line serialization at
// the TCC; rotation makes concurrent same-cv waves touch disjoint chunks.
// Diagonal strips (128/2112) keep the R17 d0 logic unchanged.
__global__ __launch_bounds__(256, 2) void k_gemm(
    const char* __restrict__ packA, const char* __restrict__ packB,
    float* __restrict__ rowsum, const float* __restrict__ pbuf,
    unsigned int* __restrict__ done, float* __restrict__ out)
{
    const int wave = threadIdx.x >> 6;
    const int lane = threadIdx.x & 63;
    const int qrow = lane >> 4, lcol = lane & 15;

    // ---- triangle strip decode: strips per q-group = 4*(32-q), offset
    //      off(q) = 130q - 2q^2 (q = rg>>2; cv in [q,32)) ----
    const int s_id = blockIdx.x * 4 + wave;          // 0..2111
    int q = (int)((130.0f - sqrtf(16900.0f - 8.0f * (float)s_id)) * 0.25f);
    while (130 * (q + 1) - 2 * (q + 1) * (q + 1) <= s_id) ++q;
    while (130 * q - 2 * q * q > s_id) --q;
    const int rem = s_id - (130 * q - 2 * q * q);
    const int w   = 32 - q;
    const int rg  = 4 * q + rem / w;                 // 64-row group, 0..127
    const int cv  = q + rem % w;                     // 256-col split, q..31
    const int diag = (cv == q);
    const int d0   = diag ? ((rg & 3) * 4) : 0;      // first step (diag only)
    const int rot  = diag ? 0 : (rg & 15);           // step rotation (off-diag)

    // A fragments: 16 coalesced 512 B loads (rows rg*64..+63, all K)
    long afrag[4][4];
    #pragma unroll
    for (int mi = 0; mi < 4; ++mi)
        #pragma unroll
        for (int ks = 0; ks < 4; ++ks)
            afrag[mi][ks] = *(const long*)(packA
                + (size_t)(rg * 4 + mi) * 2048 + ks * 512 + lane * 8);

    float rsum[4][4];
    #pragma unroll
    for (int mi = 0; mi < 4; ++mi)
        #pragma unroll
        for (int r = 0; r < 4; ++r) rsum[mi][r] = 0.0f;

    const char* Bb = packB + (size_t)(cv * 16) * 2048 + lane * 8;

    #pragma unroll 4
    for (int t = d0; t < 16; ++t) {                  // 16-col steps
        const int s = diag ? t : ((t + rot) & 15);   // rotated B order
        const char* bp = Bb + (size_t)s * 2048;
        long bfrag[4];
        #pragma unroll
        for (int ks = 0; ks < 4; ++ks)
            bfrag[ks] = *(const long*)(bp + ks * 512);

        f32x4 acc[4];
        const f32x4 zero = {0.0f, 0.0f, 0.0f, 0.0f};
        #pragma unroll
        for (int mi = 0; mi < 4; ++mi) acc[mi] = zero;
        #pragma unroll
        for (int ks = 0; ks < 4; ++ks)
            #pragma unroll
            for (int mi = 0; mi < 4; ++mi)
                acc[mi] = __builtin_amdgcn_mfma_f32_16x16x32_fp8_fp8(
                    afrag[mi][ks], bfrag[ks], acc[mi], 0, 0, 0);

        // exp once; accumulate row-sums always, col-sums when off-diagonal
        float cs = 0.0f;
        #pragma unroll
        for (int mi = 0; mi < 4; ++mi)
            #pragma unroll
            for (int r = 0; r < 4; ++r) {
                const float e = __builtin_amdgcn_exp2f(acc[mi][r]);
                rsum[mi][r] += e;
                cs += e;
            }
        if (!diag || t >= d0 + 4) {     // wave-uniform branch
            cs += __shfl_xor(cs, 16, 64);
            cs += __shfl_xor(cs, 32, 64);
            if (qrow == 0)
                atomicAdd(&rowsum[cv * 256 + s * 16 + lcol], cs);
        }
    }

    // row-direction reduction over the 16 col-lanes, one atomic per row
    #pragma unroll
    for (int mi = 0; mi < 4; ++mi)
        #pragma unroll
        for (int r = 0; r < 4; ++r) {
            float v = rsum[mi][r];
            v += __shfl_xor(v, 1, 64);
            v += __shfl_xor(v, 2, 64);
            v += __shfl_xor(v, 4, 64);
            v += __shfl_xor(v, 8, 64);
            if (lcol == 0)
                atomicAdd(&rowsum[rg * 64 + mi * 16 + qrow * 4 + r], v);
        }

    // ---- last-block finalize; no producer-side fence (R11-R17 validated) ---
    __syncthreads();            // compiler drains vmcnt(0) before s_barrier
    __shared__ int is_last;
    if (threadIdx.x == 0) {
        unsigned old = __hip_atomic_fetch_add(done, 1u, __ATOMIC_RELAXED,
                                              __HIP_MEMORY_SCOPE_AGENT);
        is_last = (old == GBLK - 1);
    }
    __syncthreads();
    if (!is_last) return;
    __threadfence();            // acquire side only, once

    // loss_k = (log2(rowsum_k + 2^(p*C1)) - p*C1) * ln2   [v_log_f32 is LOG2]
    float lsum = 0.0f;
    for (int r = threadIdx.x; r < NROWS; r += 256) {
        float rs = __hip_atomic_load(&rowsum[r], __ATOMIC_RELAXED, __HIP_MEMORY_SCOPE_AGENT);
        float pc = pbuf[r] * C1;
        float S  = rs + __builtin_amdgcn_exp2f(pc);
        lsum += (__builtin_amdgcn_logf(S) - pc) * LN2;
    }
    #pragma unroll
    for (int m = 32; m >= 1; m >>= 1) lsum += __shfl_xor(lsum, m, 64);
    __shared__ float part[4];
    if (lane == 0) part[wave] = lsum;
    __syncthreads();
    if (threadIdx.x == 0)
        out[0] = (part[0] + part[1] + part[2] + part[3]) * (1.0f / (float)NROWS);
}

extern "C" void kernel_launch(void* const* d_in, const int* in_sizes, int n_in,
                              void* d_out, int out_size, void* d_ws, size_t ws_size,
                              hipStream_t stream)
{
    const float* zi = (const float*)d_in[0];
    const float* zj = (const float*)d_in[1];
    float* out = (float*)d_out;

    // ws: packA 1MB | packB 1MB | rowsum f32[8192] | pbuf f32[8192] | done
    char*  packA  = (char*)d_ws;
    char*  packB  = packA + (size_t)NROWS * 128;
    float* rowsum = (float*)(packB + (size_t)NROWS * 128);
    float* pbuf   = rowsum + NROWS;
    unsigned int* done = (unsigned int*)(pbuf + NROWS);

    k_normalize<<<NROWS / 16, 256, 0, stream>>>(zi, zj, packA, packB, rowsum, pbuf, done);
    k_gemm<<<GBLK, 256, 0, stream>>>(packA, packB, rowsum, pbuf, done, out);
}